// Round 11
// baseline (408.427 us; speedup 1.0000x reference)
//
#include <hip/hip_runtime.h>

#define N_CHR 50000
#define E_CHR 500000
#define N_SLV 30000
#define E_SLV 300000
#define E_TOT (E_CHR + E_SLV)
#define BATCH_B 256
#define FEAT 64
#define DIM 128
#define HALF 64
#define ENSN 3
#define CB_CHR ((N_CHR + 255) / 256)
#define CB_SLV ((N_SLV + 255) / 256)
#define CB_TOT (CB_CHR + CB_SLV)
#define NBLK 128
#define SLOTS (NBLK * 4)
#define CHUNK ((E_TOT + NBLK - 1) / NBLK)
#define REP_SZ (BATCH_B * 2 * ENSN * HALF)

typedef unsigned int u32;
typedef unsigned short u16;
typedef __attribute__((ext_vector_type(8))) short short8;
typedef __attribute__((ext_vector_type(4))) float floatx4;
typedef __attribute__((ext_vector_type(4))) unsigned int u32x4;

// ---------------- bf16 helpers (round-to-nearest-even) ----------------

__device__ inline u16 f2b(float f) {
    u32 u = __builtin_bit_cast(u32, f);
    u += 0x7FFFu + ((u >> 16) & 1u);
    return (u16)(u >> 16);
}
__device__ inline float b2f_lo(u32 v) { return __builtin_bit_cast(float, v << 16); }
__device__ inline float b2f_hi(u32 v) { return __builtin_bit_cast(float, v & 0xFFFF0000u); }
__device__ inline u32 packb(float a, float b) { return (u32)f2b(a) | ((u32)f2b(b) << 16); }

__device__ inline void acc8(float* a, u32x4 v) {
    a[0] += b2f_lo(v.x); a[1] += b2f_hi(v.x);
    a[2] += b2f_lo(v.y); a[3] += b2f_hi(v.y);
    a[4] += b2f_lo(v.z); a[5] += b2f_hi(v.z);
    a[6] += b2f_lo(v.w); a[7] += b2f_hi(v.w);
}

// ---------------- input convert (also zeros btot for the CSR build) ----------------

__global__ void xconv_k(const float* __restrict__ xc, const float* __restrict__ xs,
                        u16* __restrict__ oc, u16* __restrict__ os, int* __restrict__ btot) {
    if (blockIdx.x == 0)
        for (int i = threadIdx.x; i < CB_TOT; i += 256) btot[i] = 0;
    const int nc = N_CHR * FEAT, ns = N_SLV * FEAT;
    int i = blockIdx.x * blockDim.x + threadIdx.x;
    int stride = gridDim.x * blockDim.x;
    for (; i < nc + ns; i += stride) {
        if (i < nc) oc[i] = f2b(xc[i]);
        else os[i - nc] = f2b(xs[i - nc]);
    }
}

// ---------------- all 6 weight convert+transpose in one launch ----------------

__global__ void wconv6_k(const float* __restrict__ cW0, const float* __restrict__ cW1,
                         const float* __restrict__ cW2, const float* __restrict__ sW0,
                         const float* __restrict__ sW1, const float* __restrict__ sW2,
                         u16* __restrict__ cW0t, u16* __restrict__ cW1t, u16* __restrict__ cW2t,
                         u16* __restrict__ sW0t, u16* __restrict__ sW1t, u16* __restrict__ sW2t) {
    int z = blockIdx.z, e = blockIdx.y;
    const float* W; u16* Wt; int K, N;
    switch (z) {
        case 0: W = cW0; Wt = cW0t; K = FEAT; N = DIM;  break;
        case 1: W = cW1; Wt = cW1t; K = DIM;  N = DIM;  break;
        case 2: W = cW2; Wt = cW2t; K = DIM;  N = HALF; break;
        case 3: W = sW0; Wt = sW0t; K = FEAT; N = DIM;  break;
        case 4: W = sW1; Wt = sW1t; K = DIM;  N = DIM;  break;
        default: W = sW2; Wt = sW2t; K = DIM; N = HALF; break;
    }
    int idx = blockIdx.x * 256 + threadIdx.x;
    if (idx >= K * N) return;
    int k = idx / N, nn = idx - k * N;
    Wt[((size_t)e * N + nn) * K + k] = f2b(W[(size_t)e * K * N + idx]);
}

// ---------------- CSR build: two-level bucketed counting sort ----------------
// pack: src | ((dst & 255) << 17). Per-WAVE histograms/cursors.

__global__ __launch_bounds__(256) void hist_blocks_k(
        const int* __restrict__ cdst, const int* __restrict__ sdst,
        int* __restrict__ gh, int* __restrict__ btot, float* __restrict__ rep) {
    // zero rep (consumed much later by agg3pool_k)
    for (int i = blockIdx.x * 256 + threadIdx.x; i < REP_SZ; i += NBLK * 256) rep[i] = 0.f;
    __shared__ int h[4][CB_TOT];
    int blk = blockIdx.x, t = threadIdx.x, wv = t >> 6;
    for (int i = t; i < 4 * CB_TOT; i += 256) ((int*)h)[i] = 0;
    __syncthreads();
    int s = blk * CHUNK, e = s + CHUNK;
    if (e > E_TOT) e = E_TOT;
    for (int i = s + t; i < e; i += 256) {
        int bkt = (i < E_CHR) ? (cdst[i] >> 8) : (CB_CHR + (sdst[i - E_CHR] >> 8));
        atomicAdd(&h[wv][bkt], 1);
    }
    __syncthreads();
    for (int j = t; j < CB_TOT; j += 256) {
        int s0 = h[0][j], s1 = h[1][j], s2 = h[2][j], s3 = h[3][j];
        gh[j * SLOTS + blk * 4 + 0] = s0;
        gh[j * SLOTS + blk * 4 + 1] = s1;
        gh[j * SLOTS + blk * 4 + 2] = s2;
        gh[j * SLOTS + blk * 4 + 3] = s3;
        int tot = s0 + s1 + s2 + s3;
        if (tot) atomicAdd(&btot[j], tot);
    }
}

__global__ void coarse_scan_k(const int* __restrict__ cnt, int* __restrict__ off) {
    int t = threadIdx.x;           // 64 threads
    const int PER = (CB_TOT + 63) / 64;
    int loc[PER];
    int sum = 0;
    int s = t * PER;
#pragma unroll
    for (int k = 0; k < PER; k++) {
        int i = s + k;
        int v = (i < CB_TOT) ? cnt[i] : 0;
        loc[k] = sum;
        sum += v;
    }
    int inc = sum;
#pragma unroll
    for (int o = 1; o < 64; o <<= 1) {
        int sh = __shfl_up(inc, o, 64);
        if (t >= o) inc += sh;
    }
    int pre = inc - sum;
#pragma unroll
    for (int k = 0; k < PER; k++) {
        int i = s + k;
        if (i < CB_TOT) off[i] = pre + loc[k];
    }
    if (t == 63) off[CB_TOT] = inc;
}

__device__ inline int block_exscan(int v) {
    int lane = threadIdx.x & 63, wv = threadIdx.x >> 6;
    int inc = v;
#pragma unroll
    for (int o = 1; o < 64; o <<= 1) {
        int t = __shfl_up(inc, o, 64);
        if (lane >= o) inc += t;
    }
    __shared__ int ws[4];
    if (lane == 63) ws[wv] = inc;
    __syncthreads();
    if (threadIdx.x == 0) {
        int c = 0;
#pragma unroll
        for (int k = 0; k < 4; k++) { int t = ws[k]; ws[k] = c; c += t; }
    }
    __syncthreads();
    int r = ws[wv] + inc - v;
    __syncthreads();
    return r;
}

__global__ __launch_bounds__(256) void block_base_k(int* __restrict__ gh,
                                                    const int* __restrict__ coff) {
    int j = blockIdx.x, t = threadIdx.x;
    int v0 = gh[j * SLOTS + 2 * t], v1 = gh[j * SLOTS + 2 * t + 1];
    int p = block_exscan(v0 + v1);
    gh[j * SLOTS + 2 * t] = coff[j] + p;
    gh[j * SLOTS + 2 * t + 1] = coff[j] + p + v0;
}

__global__ __launch_bounds__(256) void scatter2_k(
        const int* __restrict__ cei, const int* __restrict__ sei,
        const int* __restrict__ gh, u32* __restrict__ staging) {
    __shared__ int cur[4][CB_TOT];
    int blk = blockIdx.x, t = threadIdx.x, wv = t >> 6;
    for (int i = t; i < 4 * CB_TOT; i += 256) {
        int w = i / CB_TOT, j = i - w * CB_TOT;
        ((int*)cur)[i] = gh[j * SLOTS + blk * 4 + w];
    }
    __syncthreads();
    int s = blk * CHUNK, e = s + CHUNK;
    if (e > E_TOT) e = E_TOT;
    for (int i = s + t; i < e; i += 256) {
        int src, dst, bkt;
        if (i < E_CHR) {
            src = cei[i]; dst = cei[E_CHR + i]; bkt = dst >> 8;
        } else {
            int j2 = i - E_CHR;
            src = sei[j2]; dst = sei[E_SLV + j2]; bkt = CB_CHR + (dst >> 8);
        }
        int p = atomicAdd(&cur[wv][bkt], 1);
        staging[p] = (u32)src | ((u32)(dst & 255) << 17);
    }
}

__global__ __launch_bounds__(256) void bucket_sort_k(
        const u32* __restrict__ staging, const int* __restrict__ coff,
        int* __restrict__ off_c, int* __restrict__ off_s,
        int* __restrict__ csr_c, int* __restrict__ csr_s) {
    int b = blockIdx.x, t = threadIdx.x, wv = t >> 6;
    int isS = b >= CB_CHR;
    int base = coff[b], end = coff[b + 1];
    int n = isS ? N_SLV : N_CHR;
    int* off = isS ? off_s : off_c;
    int* csr = isS ? csr_s : csr_c;
    int outBase = isS ? base - E_CHR : base;
    int nodeBase = (isS ? (b - CB_CHR) : b) << 8;
    __shared__ int h4[4][256];
    __shared__ int cur[256];
    h4[0][t] = 0; h4[1][t] = 0; h4[2][t] = 0; h4[3][t] = 0;
    __syncthreads();
    for (int i = base + t; i < end; i += 256)
        atomicAdd(&h4[wv][staging[i] >> 17], 1);
    __syncthreads();
    int tot = h4[0][t] + h4[1][t] + h4[2][t] + h4[3][t];
    int p = block_exscan(tot);
    int node = nodeBase + t;
    if (node <= n) off[node] = outBase + p;
    cur[t] = p;
    __syncthreads();
    for (int i = base + t; i < end; i += 256) {
        u32 v = staging[i];
        int pos = atomicAdd(&cur[v >> 17], 1);
        csr[outBase + pos] = (int)(v & 0x1FFFFu);
    }
}

// ---------------- FUSED layer-1 agg + GEMM1: h1[e] = relu(agg(x) @ W0[e]) ----------------

__global__ __launch_bounds__(256) void agg1gemm_k(
        const u16* __restrict__ Xc, const int* __restrict__ offc, const int* __restrict__ csrc,
        const u16* __restrict__ W0c, u16* __restrict__ Yc, int nc,
        const u16* __restrict__ Xs, const int* __restrict__ offs, const int* __restrict__ csrs,
        const u16* __restrict__ W0s, u16* __restrict__ Ys, int ns) {
    __shared__ u32x4 at4[64 * 8];      // 8 KB agg tile, swizzled
    __shared__ u32x4 wt4[128 * 8];     // 16 KB one-ens W0t, swizzled
    int z = blockIdx.z;
    int n = z ? ns : nc;
    const int* off = z ? offs : offc;
    const int* csr = z ? csrs : csrc;
    const u32x4* X4 = (const u32x4*)(z ? Xs : Xc);
    const u16* W0 = z ? W0s : W0c;
    u16* Y = z ? Ys : Yc;
    int i0 = blockIdx.x * 64;
    if (i0 >= n) return;
    int t = threadIdx.x;
    int nl = t >> 2, c0 = t & 3;
    int i = i0 + nl;
    float a[16] = {0,0,0,0,0,0,0,0,0,0,0,0,0,0,0,0};
    if (i < n) {
        int s = off[i], e2 = off[i + 1], j = s;
        for (; j + 1 < e2; j += 2) {
            size_t r0 = (size_t)csr[j] * 8, r1 = (size_t)csr[j + 1] * 8;
            u32x4 v0 = X4[r0 + c0], v1 = X4[r0 + c0 + 4];
            u32x4 w0 = X4[r1 + c0], w1 = X4[r1 + c0 + 4];
            acc8(a, v0); acc8(a + 8, v1); acc8(a, w0); acc8(a + 8, w1);
        }
        if (j < e2) {
            size_t r0 = (size_t)csr[j] * 8;
            acc8(a, X4[r0 + c0]); acc8(a + 8, X4[r0 + c0 + 4]);
        }
    }
    u32x4 o0, o1;
    o0.x = packb(a[0], a[1]);  o0.y = packb(a[2], a[3]);
    o0.z = packb(a[4], a[5]);  o0.w = packb(a[6], a[7]);
    o1.x = packb(a[8], a[9]);  o1.y = packb(a[10], a[11]);
    o1.z = packb(a[12], a[13]); o1.w = packb(a[14], a[15]);
    int sw = nl & 7;
    at4[nl * 8 + (c0 ^ sw)] = o0;
    at4[nl * 8 + ((c0 + 4) ^ sw)] = o1;
    int wave = t >> 6, lane = t & 63, quad = lane >> 4, nq = lane & 15;
    int arow = wave * 16 + nq;
    for (int e = 0; e < ENSN; e++) {
        __syncthreads();
        const u16* We = W0 + (size_t)e * DIM * FEAT;
        for (int ci = t; ci < 128 * 8; ci += 256) {
            int row = ci >> 3, c = ci & 7;
            wt4[row * 8 + (c ^ (row & 7))] = *(const u32x4*)(We + (size_t)row * FEAT + c * 8);
        }
        __syncthreads();
        floatx4 acc[8];
#pragma unroll
        for (int tt = 0; tt < 8; tt++) acc[tt] = (floatx4)(0.f);
#pragma unroll
        for (int kt = 0; kt < 2; kt++) {
            int ck = kt * 4 + quad;
            short8 af = *(const short8*)&at4[arow * 8 + (ck ^ (arow & 7))];
#pragma unroll
            for (int tt = 0; tt < 8; tt++) {
                int br = tt * 16 + nq;
                short8 bf = *(const short8*)&wt4[br * 8 + (ck ^ (br & 7))];
                acc[tt] = __builtin_amdgcn_mfma_f32_16x16x32_bf16(af, bf, acc[tt], 0, 0, 0);
            }
        }
        u16* Ye = Y + (size_t)e * (size_t)n * DIM;
#pragma unroll
        for (int tt = 0; tt < 8; tt++)
#pragma unroll
            for (int r = 0; r < 4; r++) {
                int row = i0 + wave * 16 + quad * 4 + r;
                if (row < n) Ye[(size_t)row * DIM + tt * 16 + nq] = f2b(fmaxf(acc[tt][r], 0.f));
            }
    }
}

// ---------------- FUSED layer-2 agg + GEMM2 + GEMM3: p3 = relu(agg(h1)@W1) @ W2 ----------------
// Gather lands directly in A-fragment registers: lane (nq,quad) owns rows m0+{0,16}+nq
// and chunks {0,4,8,12}+quad of the 16-chunk row — exactly its MFMA A operand.
// No LDS for A, no intermediate buffer. GEMM3 via swizzled-LDS h2 round-trip as before.

__global__ __launch_bounds__(256) void agg2gemm23_k(
        const u16* __restrict__ Hc, const int* __restrict__ offc, const int* __restrict__ csrc,
        const u16* __restrict__ W1c, const u16* __restrict__ W2c, u16* __restrict__ Yc, int nc,
        const u16* __restrict__ Hs, const int* __restrict__ offs, const int* __restrict__ csrs,
        const u16* __restrict__ W1s, const u16* __restrict__ W2s, u16* __restrict__ Ys, int ns) {
    __shared__ u16 wlds[DIM * DIM];        // 32 KB: W1 then W2 (swizzled)
    __shared__ u16 hlds[4 * 32 * DIM];     // 32 KB: per-wave h2 tiles (swizzled)
    const int z = blockIdx.z, e = blockIdx.y;
    const int n = z ? ns : nc;
    const int* off = z ? offs : offc;
    const int* csr = z ? csrs : csrc;
    const u32x4* He = (const u32x4*)((z ? Hs : Hc) + (size_t)e * (size_t)n * DIM);  // 16 chunks/row
    const u16* W1 = (z ? W1s : W1c) + (size_t)e * DIM * DIM;
    const u16* W2 = (z ? W2s : W2c) + (size_t)e * HALF * DIM;
    u16* Ye = (z ? Ys : Yc) + (size_t)e * (size_t)n * HALF;
    // stage W1 (independent of gather; barrier after gather)
    for (int c = threadIdx.x; c < DIM * (DIM / 8); c += 256) {
        int row = c >> 4, seg = c & 15;
        *(short8*)(wlds + row * DIM + ((seg ^ (row & 15)) << 3)) =
            *(const short8*)(W1 + (size_t)row * DIM + (seg << 3));
    }
    int wave = threadIdx.x >> 6, lane = threadIdx.x & 63;
    int quad = lane >> 4, nq = lane & 15;
    int m0 = blockIdx.x * 128 + wave * 32;
    // ---- gather phase: agg rows into A-fragment registers ----
    float ag[2][4][8];
#pragma unroll
    for (int rg = 0; rg < 2; rg++)
#pragma unroll
        for (int kt = 0; kt < 4; kt++)
#pragma unroll
            for (int k = 0; k < 8; k++) ag[rg][kt][k] = 0.f;
#pragma unroll
    for (int rg = 0; rg < 2; rg++) {
        int r = m0 + rg * 16 + nq;
        if (r < n) {
            int s = off[r], e2 = off[r + 1], j = s;
            for (; j + 1 < e2; j += 2) {
                size_t b0 = (size_t)csr[j] * 16 + quad, b1 = (size_t)csr[j + 1] * 16 + quad;
                u32x4 v0 = He[b0], v1 = He[b0 + 4], v2 = He[b0 + 8], v3 = He[b0 + 12];
                u32x4 w0 = He[b1], w1 = He[b1 + 4], w2 = He[b1 + 8], w3 = He[b1 + 12];
                acc8(ag[rg][0], v0); acc8(ag[rg][1], v1);
                acc8(ag[rg][2], v2); acc8(ag[rg][3], v3);
                acc8(ag[rg][0], w0); acc8(ag[rg][1], w1);
                acc8(ag[rg][2], w2); acc8(ag[rg][3], w3);
            }
            if (j < e2) {
                size_t b0 = (size_t)csr[j] * 16 + quad;
                acc8(ag[rg][0], He[b0]);     acc8(ag[rg][1], He[b0 + 4]);
                acc8(ag[rg][2], He[b0 + 8]); acc8(ag[rg][3], He[b0 + 12]);
            }
        }
    }
    __syncthreads();   // W1 staged
    // ---- GEMM2: h2 = relu(A @ W1), A from registers ----
    floatx4 acc[2][8];
#pragma unroll
    for (int rg = 0; rg < 2; rg++)
#pragma unroll
        for (int t = 0; t < 8; t++) acc[rg][t] = (floatx4)(0.f);
#pragma unroll
    for (int kt = 0; kt < 4; kt++) {
        short8 a[2];
#pragma unroll
        for (int rg = 0; rg < 2; rg++) {
            u32x4 t4;
            t4.x = packb(ag[rg][kt][0], ag[rg][kt][1]);
            t4.y = packb(ag[rg][kt][2], ag[rg][kt][3]);
            t4.z = packb(ag[rg][kt][4], ag[rg][kt][5]);
            t4.w = packb(ag[rg][kt][6], ag[rg][kt][7]);
            a[rg] = __builtin_bit_cast(short8, t4);
        }
#pragma unroll
        for (int t = 0; t < 8; t++) {
            int rb = t * 16 + nq;
            short8 b = *(const short8*)(wlds + rb * DIM + ((((kt << 2) + quad) ^ nq) << 3));
#pragma unroll
            for (int rg = 0; rg < 2; rg++)
                acc[rg][t] = __builtin_amdgcn_mfma_f32_16x16x32_bf16(a[rg], b, acc[rg][t], 0, 0, 0);
        }
    }
    // h2 (C-layout) -> swizzled LDS, relu
    u16* hw = hlds + wave * 32 * DIM;
#pragma unroll
    for (int rg = 0; rg < 2; rg++)
#pragma unroll
        for (int t = 0; t < 8; t++)
#pragma unroll
            for (int r = 0; r < 4; r++) {
                int rl = rg * 16 + quad * 4 + r;
                int col = t * 16 + nq;
                hw[rl * DIM + (((col >> 3) ^ (rl & 15)) << 3) + (col & 7)] =
                    f2b(fmaxf(acc[rg][t][r], 0.f));
            }
    __syncthreads();
    // stage W2 into wlds rows 0..63
    for (int c = threadIdx.x; c < HALF * (DIM / 8); c += 256) {
        int row = c >> 4, seg = c & 15;
        *(short8*)(wlds + row * DIM + ((seg ^ (row & 15)) << 3)) =
            *(const short8*)(W2 + (size_t)row * DIM + (seg << 3));
    }
    __syncthreads();
    // ---- GEMM3: p3 = h2 @ W2 ----
    floatx4 acc2[2][4];
#pragma unroll
    for (int rg = 0; rg < 2; rg++)
#pragma unroll
        for (int t = 0; t < 4; t++) acc2[rg][t] = (floatx4)(0.f);
#pragma unroll
    for (int kt = 0; kt < 4; kt++) {
        int k0q = (kt << 2) + quad;
        short8 a[2];
#pragma unroll
        for (int rg = 0; rg < 2; rg++) {
            int rl = rg * 16 + nq;
            a[rg] = *(const short8*)(hw + rl * DIM + ((k0q ^ (rl & 15)) << 3));
        }
#pragma unroll
        for (int t = 0; t < 4; t++) {
            int rb = t * 16 + nq;
            short8 b = *(const short8*)(wlds + rb * DIM + ((k0q ^ nq) << 3));
#pragma unroll
            for (int rg = 0; rg < 2; rg++)
                acc2[rg][t] = __builtin_amdgcn_mfma_f32_16x16x32_bf16(a[rg], b, acc2[rg][t], 0, 0, 0);
        }
    }
#pragma unroll
    for (int rg = 0; rg < 2; rg++)
#pragma unroll
        for (int t = 0; t < 4; t++)
#pragma unroll
            for (int r = 0; r < 4; r++) {
                int row = m0 + rg * 16 + quad * 4 + r;
                if (row < n) Ye[(size_t)row * HALF + t * 16 + nq] = f2b(acc2[rg][t][r]);
            }
}

// ---------------- layer-3 agg + relu + pool, PER-ENS (un-folded; R8 lesson) ----------------

__global__ __launch_bounds__(256) void agg3pool_k(
        const u16* __restrict__ Pc, const int* __restrict__ offc, const int* __restrict__ csrc,
        const int* __restrict__ batc, int nc,
        const u16* __restrict__ Ps, const int* __restrict__ offs, const int* __restrict__ csrs,
        const int* __restrict__ bats, int ns,
        float* __restrict__ rep) {
    int z = blockIdx.z, e = blockIdx.y;
    int n = z ? ns : nc;
    const int* off = z ? offs : offc;
    const int* csr = z ? csrs : csrc;
    const int* batch = z ? bats : batc;
    const u32x4* Pe = (const u32x4*)((z ? Ps : Pc) + (size_t)e * (size_t)n * HALF);  // 8 chunks/row
    int i0 = blockIdx.x * 32;
    int nl = threadIdx.x >> 3, l8 = threadIdx.x & 7;
    int i = i0 + nl;
    float a[8] = {0,0,0,0,0,0,0,0};
    if (i < n) {
        int s = off[i], e2 = off[i + 1], j = s;
        for (; j + 3 < e2; j += 4) {
            u32x4 v0 = Pe[(size_t)csr[j] * 8 + l8];
            u32x4 v1 = Pe[(size_t)csr[j + 1] * 8 + l8];
            u32x4 v2 = Pe[(size_t)csr[j + 2] * 8 + l8];
            u32x4 v3 = Pe[(size_t)csr[j + 3] * 8 + l8];
            acc8(a, v0); acc8(a, v1); acc8(a, v2); acc8(a, v3);
        }
        for (; j < e2; j++) acc8(a, Pe[(size_t)csr[j] * 8 + l8]);
    }
    __shared__ float sm[32][64];
    __shared__ int gb[32];
#pragma unroll
    for (int k = 0; k < 8; k++) sm[nl][l8 * 8 + k] = fmaxf(a[k], 0.f);
    if (threadIdx.x < 32) gb[threadIdx.x] = (i0 + (int)threadIdx.x < n) ? batch[i0 + threadIdx.x] : -1;
    __syncthreads();
    if (threadIdx.x < 64) {
        int f = threadIdx.x;
        int colbase = z * (ENSN * HALF) + e * HALF + f;
        float acc = 0.f;
        int g = -2;
        for (int k = 0; k < 32; k++) {
            int gg = gb[k];
            if (gg != g) {
                if (g >= 0) atomicAdd(&rep[g * (2 * ENSN * HALF) + colbase], acc);
                acc = 0.f;
                g = gg;
            }
            if (gg >= 0) acc += sm[k][f];
        }
        if (g >= 0) atomicAdd(&rep[g * (2 * ENSN * HALF) + colbase], acc);
    }
}

// ---------------- fused heads + final MLP: one block per graph ----------------

__global__ __launch_bounds__(256) void headfinal_k(
        const float* __restrict__ rep,
        const float* __restrict__ cW, const float* __restrict__ cB,
        const float* __restrict__ sW, const float* __restrict__ sB,
        const float* __restrict__ W1, const float* __restrict__ b1,
        const float* __restrict__ W2, const float* __restrict__ b2,
        float* __restrict__ out) {
    int b = blockIdx.x, t = threadIdx.x;
    __shared__ float r[2 * ENSN * HALF];
    __shared__ float hg[2 * ENSN * DIM];
    __shared__ float red[DIM];
    for (int i = t; i < 2 * ENSN * HALF; i += 256) r[i] = rep[b * (2 * ENSN * HALF) + i];
    __syncthreads();
    for (int o = t; o < 2 * ENSN * DIM; o += 256) {
        int head = o >> 7, c = o & 127;
        int branch = head / ENSN, e = head - branch * ENSN;
        const float* W = (branch ? sW : cW) + (size_t)e * HALF * DIM;
        const float* rr = r + branch * (ENSN * HALF) + e * HALF;
        float acc = (branch ? sB : cB)[e * DIM + c];
#pragma unroll
        for (int k = 0; k < HALF; k++) acc = fmaf(rr[k], W[k * DIM + c], acc);
        hg[o] = fmaxf(acc, 0.f);
    }
    __syncthreads();
    if (t < DIM) {
        float acc = b1[t];
        for (int k = 0; k < 2 * ENSN * DIM; k++) acc = fmaf(hg[k], W1[k * DIM + t], acc);
        red[t] = fmaxf(acc, 0.f) * W2[t];
    }
    __syncthreads();
    if (t < 64) {
        float v = red[t] + red[t + 64];
#pragma unroll
        for (int o = 32; o > 0; o >>= 1) v += __shfl_down(v, o, 64);
        if (t == 0) out[b] = v + b2[0];
    }
}

// ---------------- host ----------------

extern "C" void kernel_launch(void* const* d_in, const int* in_sizes, int n_in,
                              void* d_out, int out_size, void* d_ws, size_t ws_size,
                              hipStream_t stream) {
    const float* chr_x = (const float*)d_in[0];
    const float* slv_x = (const float*)d_in[1];
    const int* chr_ei = (const int*)d_in[2];
    const int* slv_ei = (const int*)d_in[3];
    const int* chr_batch = (const int*)d_in[4];
    const int* slv_batch = (const int*)d_in[5];
    const float* chr_W0 = (const float*)d_in[6];
    const float* chr_W1 = (const float*)d_in[7];
    const float* chr_W2 = (const float*)d_in[8];
    const float* slv_W0 = (const float*)d_in[9];
    const float* slv_W1 = (const float*)d_in[10];
    const float* slv_W2 = (const float*)d_in[11];
    const float* cfc_W = (const float*)d_in[12];
    const float* cfc_b = (const float*)d_in[13];
    const float* sfc_W = (const float*)d_in[14];
    const float* sfc_b = (const float*)d_in[15];
    const float* fc1_W = (const float*)d_in[16];
    const float* fc1_b = (const float*)d_in[17];
    const float* fc2_W = (const float*)d_in[18];
    const float* fc2_b = (const float*)d_in[19];
    float* out = (float*)d_out;

    char* w = (char*)d_ws;
    auto carve = [&](size_t bytes) {
        void* p = (void*)w;
        w += (bytes + 255) & ~(size_t)255;
        return p;
    };
    int* off_chr = (int*)carve((N_CHR + 1) * sizeof(int));
    int* csr_chr = (int*)carve((size_t)E_CHR * sizeof(int));
    int* off_slv = (int*)carve((N_SLV + 1) * sizeof(int));
    int* csr_slv = (int*)carve((size_t)E_SLV * sizeof(int));
    int* btot    = (int*)carve(CB_TOT * sizeof(int));
    int* coff    = (int*)carve((CB_TOT + 1) * sizeof(int));
    int* gh      = (int*)carve((size_t)CB_TOT * SLOTS * sizeof(int));
    u32* staging = (u32*)carve((size_t)E_TOT * sizeof(u32));
    u16* cW0t = (u16*)carve((size_t)ENSN * DIM * FEAT * sizeof(u16));
    u16* cW1t = (u16*)carve((size_t)ENSN * DIM * DIM * sizeof(u16));
    u16* cW2t = (u16*)carve((size_t)ENSN * HALF * DIM * sizeof(u16));
    u16* sW0t = (u16*)carve((size_t)ENSN * DIM * FEAT * sizeof(u16));
    u16* sW1t = (u16*)carve((size_t)ENSN * DIM * DIM * sizeof(u16));
    u16* sW2t = (u16*)carve((size_t)ENSN * HALF * DIM * sizeof(u16));
    u16* xb_chr = (u16*)carve((size_t)N_CHR * FEAT * sizeof(u16));
    u16* xb_slv = (u16*)carve((size_t)N_SLV * FEAT * sizeof(u16));
    float* rep = (float*)carve((size_t)REP_SZ * sizeof(float));
    u16* bufP_c = (u16*)carve((size_t)ENSN * N_CHR * DIM * sizeof(u16));   // h1
    u16* bufQ_c = (u16*)carve((size_t)ENSN * N_CHR * DIM * sizeof(u16));   // p3
    u16* bufP_s = (u16*)carve((size_t)ENSN * N_SLV * DIM * sizeof(u16));
    u16* bufQ_s = (u16*)carve((size_t)ENSN * N_SLV * DIM * sizeof(u16));

    // ---- converts (xconv also zeros btot) ----
    xconv_k<<<512, 256, 0, stream>>>(chr_x, slv_x, xb_chr, xb_slv, btot);
    wconv6_k<<<dim3(64, ENSN, 6), 256, 0, stream>>>(chr_W0, chr_W1, chr_W2,
                                                    slv_W0, slv_W1, slv_W2,
                                                    cW0t, cW1t, cW2t, sW0t, sW1t, sW2t);

    // ---- CSR build (hist also zeros rep) ----
    hist_blocks_k<<<NBLK, 256, 0, stream>>>(chr_ei + E_CHR, slv_ei + E_SLV, gh, btot, rep);
    coarse_scan_k<<<1, 64, 0, stream>>>(btot, coff);
    block_base_k<<<CB_TOT, 256, 0, stream>>>(gh, coff);
    scatter2_k<<<NBLK, 256, 0, stream>>>(chr_ei, slv_ei, gh, staging);
    bucket_sort_k<<<CB_TOT, 256, 0, stream>>>(staging, coff, off_chr, off_slv, csr_chr, csr_slv);

    // ---- branches (chr+slv via z; ens via y) ----
    agg1gemm_k<<<dim3((N_CHR + 63) / 64, 1, 2), 256, 0, stream>>>(
        xb_chr, off_chr, csr_chr, cW0t, bufP_c, N_CHR,
        xb_slv, off_slv, csr_slv, sW0t, bufP_s, N_SLV);
    agg2gemm23_k<<<dim3((N_CHR + 127) / 128, ENSN, 2), 256, 0, stream>>>(
        bufP_c, off_chr, csr_chr, cW1t, cW2t, bufQ_c, N_CHR,
        bufP_s, off_slv, csr_slv, sW1t, sW2t, bufQ_s, N_SLV);
    agg3pool_k<<<dim3((N_CHR + 31) / 32, ENSN, 2), 256, 0, stream>>>(
        bufQ_c, off_chr, csr_chr, chr_batch, N_CHR,
        bufQ_s, off_slv, csr_slv, slv_batch, N_SLV, rep);

    // ---- heads + final MLP ----
    headfinal_k<<<BATCH_B, 256, 0, stream>>>(rep, cfc_W, cfc_b, sfc_W, sfc_b,
                                             fc1_W, fc1_b, fc2_W, fc2_b, out);
}

// Round 12
// 366.738 us; speedup vs baseline: 1.1137x; 1.1137x over previous
//
#include <hip/hip_runtime.h>

#define N_CHR 50000
#define E_CHR 500000
#define N_SLV 30000
#define E_SLV 300000
#define E_TOT (E_CHR + E_SLV)
#define BATCH_B 256
#define FEAT 64
#define DIM 128
#define HALF 64
#define ENSN 3
#define CB_CHR ((N_CHR + 255) / 256)
#define CB_SLV ((N_SLV + 255) / 256)
#define CB_TOT (CB_CHR + CB_SLV)
#define NBLK 128
#define SLOTS (NBLK * 4)
#define CHUNK ((E_TOT + NBLK - 1) / NBLK)
#define REP_SZ (BATCH_B * 2 * ENSN * HALF)

typedef unsigned int u32;
typedef unsigned short u16;
typedef __attribute__((ext_vector_type(8))) short short8;
typedef __attribute__((ext_vector_type(4))) float floatx4;
typedef __attribute__((ext_vector_type(4))) unsigned int u32x4;

// ---------------- bf16 helpers (round-to-nearest-even) ----------------

__device__ inline u16 f2b(float f) {
    u32 u = __builtin_bit_cast(u32, f);
    u += 0x7FFFu + ((u >> 16) & 1u);
    return (u16)(u >> 16);
}
__device__ inline float b2f_lo(u32 v) { return __builtin_bit_cast(float, v << 16); }
__device__ inline float b2f_hi(u32 v) { return __builtin_bit_cast(float, v & 0xFFFF0000u); }
__device__ inline u32 packb(float a, float b) { return (u32)f2b(a) | ((u32)f2b(b) << 16); }

__device__ inline void acc8(float* a, u32x4 v) {
    a[0] += b2f_lo(v.x); a[1] += b2f_hi(v.x);
    a[2] += b2f_lo(v.y); a[3] += b2f_hi(v.y);
    a[4] += b2f_lo(v.z); a[5] += b2f_hi(v.z);
    a[6] += b2f_lo(v.w); a[7] += b2f_hi(v.w);
}

// ---------------- input convert (also zeros btot for the CSR build) ----------------

__global__ void xconv_k(const float* __restrict__ xc, const float* __restrict__ xs,
                        u16* __restrict__ oc, u16* __restrict__ os, int* __restrict__ btot) {
    if (blockIdx.x == 0)
        for (int i = threadIdx.x; i < CB_TOT; i += 256) btot[i] = 0;
    const int nc = N_CHR * FEAT, ns = N_SLV * FEAT;
    int i = blockIdx.x * blockDim.x + threadIdx.x;
    int stride = gridDim.x * blockDim.x;
    for (; i < nc + ns; i += stride) {
        if (i < nc) oc[i] = f2b(xc[i]);
        else os[i - nc] = f2b(xs[i - nc]);
    }
}

// ---------------- all 6 weight convert+transpose in one launch ----------------

__global__ void wconv6_k(const float* __restrict__ cW0, const float* __restrict__ cW1,
                         const float* __restrict__ cW2, const float* __restrict__ sW0,
                         const float* __restrict__ sW1, const float* __restrict__ sW2,
                         u16* __restrict__ cW0t, u16* __restrict__ cW1t, u16* __restrict__ cW2t,
                         u16* __restrict__ sW0t, u16* __restrict__ sW1t, u16* __restrict__ sW2t) {
    int z = blockIdx.z, e = blockIdx.y;
    const float* W; u16* Wt; int K, N;
    switch (z) {
        case 0: W = cW0; Wt = cW0t; K = FEAT; N = DIM;  break;
        case 1: W = cW1; Wt = cW1t; K = DIM;  N = DIM;  break;
        case 2: W = cW2; Wt = cW2t; K = DIM;  N = HALF; break;
        case 3: W = sW0; Wt = sW0t; K = FEAT; N = DIM;  break;
        case 4: W = sW1; Wt = sW1t; K = DIM;  N = DIM;  break;
        default: W = sW2; Wt = sW2t; K = DIM; N = HALF; break;
    }
    int idx = blockIdx.x * 256 + threadIdx.x;
    if (idx >= K * N) return;
    int k = idx / N, nn = idx - k * N;
    Wt[((size_t)e * N + nn) * K + k] = f2b(W[(size_t)e * K * N + idx]);
}

// ---------------- CSR build: two-level bucketed counting sort ----------------
// pack: src | ((dst & 255) << 17). Per-WAVE histograms/cursors.

__global__ __launch_bounds__(256) void hist_blocks_k(
        const int* __restrict__ cdst, const int* __restrict__ sdst,
        int* __restrict__ gh, int* __restrict__ btot, float* __restrict__ rep) {
    for (int i = blockIdx.x * 256 + threadIdx.x; i < REP_SZ; i += NBLK * 256) rep[i] = 0.f;
    __shared__ int h[4][CB_TOT];
    int blk = blockIdx.x, t = threadIdx.x, wv = t >> 6;
    for (int i = t; i < 4 * CB_TOT; i += 256) ((int*)h)[i] = 0;
    __syncthreads();
    int s = blk * CHUNK, e = s + CHUNK;
    if (e > E_TOT) e = E_TOT;
    for (int i = s + t; i < e; i += 256) {
        int bkt = (i < E_CHR) ? (cdst[i] >> 8) : (CB_CHR + (sdst[i - E_CHR] >> 8));
        atomicAdd(&h[wv][bkt], 1);
    }
    __syncthreads();
    for (int j = t; j < CB_TOT; j += 256) {
        int s0 = h[0][j], s1 = h[1][j], s2 = h[2][j], s3 = h[3][j];
        gh[j * SLOTS + blk * 4 + 0] = s0;
        gh[j * SLOTS + blk * 4 + 1] = s1;
        gh[j * SLOTS + blk * 4 + 2] = s2;
        gh[j * SLOTS + blk * 4 + 3] = s3;
        int tot = s0 + s1 + s2 + s3;
        if (tot) atomicAdd(&btot[j], tot);
    }
}

__global__ void coarse_scan_k(const int* __restrict__ cnt, int* __restrict__ off) {
    int t = threadIdx.x;           // 64 threads
    const int PER = (CB_TOT + 63) / 64;
    int loc[PER];
    int sum = 0;
    int s = t * PER;
#pragma unroll
    for (int k = 0; k < PER; k++) {
        int i = s + k;
        int v = (i < CB_TOT) ? cnt[i] : 0;
        loc[k] = sum;
        sum += v;
    }
    int inc = sum;
#pragma unroll
    for (int o = 1; o < 64; o <<= 1) {
        int sh = __shfl_up(inc, o, 64);
        if (t >= o) inc += sh;
    }
    int pre = inc - sum;
#pragma unroll
    for (int k = 0; k < PER; k++) {
        int i = s + k;
        if (i < CB_TOT) off[i] = pre + loc[k];
    }
    if (t == 63) off[CB_TOT] = inc;
}

__device__ inline int block_exscan(int v) {
    int lane = threadIdx.x & 63, wv = threadIdx.x >> 6;
    int inc = v;
#pragma unroll
    for (int o = 1; o < 64; o <<= 1) {
        int t = __shfl_up(inc, o, 64);
        if (lane >= o) inc += t;
    }
    __shared__ int ws[4];
    if (lane == 63) ws[wv] = inc;
    __syncthreads();
    if (threadIdx.x == 0) {
        int c = 0;
#pragma unroll
        for (int k = 0; k < 4; k++) { int t = ws[k]; ws[k] = c; c += t; }
    }
    __syncthreads();
    int r = ws[wv] + inc - v;
    __syncthreads();
    return r;
}

__global__ __launch_bounds__(256) void block_base_k(int* __restrict__ gh,
                                                    const int* __restrict__ coff) {
    int j = blockIdx.x, t = threadIdx.x;
    int v0 = gh[j * SLOTS + 2 * t], v1 = gh[j * SLOTS + 2 * t + 1];
    int p = block_exscan(v0 + v1);
    gh[j * SLOTS + 2 * t] = coff[j] + p;
    gh[j * SLOTS + 2 * t + 1] = coff[j] + p + v0;
}

__global__ __launch_bounds__(256) void scatter2_k(
        const int* __restrict__ cei, const int* __restrict__ sei,
        const int* __restrict__ gh, u32* __restrict__ staging) {
    __shared__ int cur[4][CB_TOT];
    int blk = blockIdx.x, t = threadIdx.x, wv = t >> 6;
    for (int i = t; i < 4 * CB_TOT; i += 256) {
        int w = i / CB_TOT, j = i - w * CB_TOT;
        ((int*)cur)[i] = gh[j * SLOTS + blk * 4 + w];
    }
    __syncthreads();
    int s = blk * CHUNK, e = s + CHUNK;
    if (e > E_TOT) e = E_TOT;
    for (int i = s + t; i < e; i += 256) {
        int src, dst, bkt;
        if (i < E_CHR) {
            src = cei[i]; dst = cei[E_CHR + i]; bkt = dst >> 8;
        } else {
            int j2 = i - E_CHR;
            src = sei[j2]; dst = sei[E_SLV + j2]; bkt = CB_CHR + (dst >> 8);
        }
        int p = atomicAdd(&cur[wv][bkt], 1);
        staging[p] = (u32)src | ((u32)(dst & 255) << 17);
    }
}

__global__ __launch_bounds__(256) void bucket_sort_k(
        const u32* __restrict__ staging, const int* __restrict__ coff,
        int* __restrict__ off_c, int* __restrict__ off_s,
        int* __restrict__ csr_c, int* __restrict__ csr_s) {
    int b = blockIdx.x, t = threadIdx.x, wv = t >> 6;
    int isS = b >= CB_CHR;
    int base = coff[b], end = coff[b + 1];
    int n = isS ? N_SLV : N_CHR;
    int* off = isS ? off_s : off_c;
    int* csr = isS ? csr_s : csr_c;
    int outBase = isS ? base - E_CHR : base;
    int nodeBase = (isS ? (b - CB_CHR) : b) << 8;
    __shared__ int h4[4][256];
    __shared__ int cur[256];
    h4[0][t] = 0; h4[1][t] = 0; h4[2][t] = 0; h4[3][t] = 0;
    __syncthreads();
    for (int i = base + t; i < end; i += 256)
        atomicAdd(&h4[wv][staging[i] >> 17], 1);
    __syncthreads();
    int tot = h4[0][t] + h4[1][t] + h4[2][t] + h4[3][t];
    int p = block_exscan(tot);
    int node = nodeBase + t;
    if (node <= n) off[node] = outBase + p;
    cur[t] = p;
    __syncthreads();
    for (int i = base + t; i < end; i += 256) {
        u32 v = staging[i];
        int pos = atomicAdd(&cur[v >> 17], 1);
        csr[outBase + pos] = (int)(v & 0x1FFFFu);
    }
}

// ---------------- FUSED layer-1 agg + GEMM1: h1[e] = relu(agg(x) @ W0[e]) ----------------
// LDS only 24 KB -> high occupancy preserved for the gather phase.

__global__ __launch_bounds__(256) void agg1gemm_k(
        const u16* __restrict__ Xc, const int* __restrict__ offc, const int* __restrict__ csrc,
        const u16* __restrict__ W0c, u16* __restrict__ Yc, int nc,
        const u16* __restrict__ Xs, const int* __restrict__ offs, const int* __restrict__ csrs,
        const u16* __restrict__ W0s, u16* __restrict__ Ys, int ns) {
    __shared__ u32x4 at4[64 * 8];      // 8 KB agg tile, swizzled
    __shared__ u32x4 wt4[128 * 8];     // 16 KB one-ens W0t, swizzled
    int z = blockIdx.z;
    int n = z ? ns : nc;
    const int* off = z ? offs : offc;
    const int* csr = z ? csrs : csrc;
    const u32x4* X4 = (const u32x4*)(z ? Xs : Xc);
    const u16* W0 = z ? W0s : W0c;
    u16* Y = z ? Ys : Yc;
    int i0 = blockIdx.x * 64;
    if (i0 >= n) return;
    int t = threadIdx.x;
    int nl = t >> 2, c0 = t & 3;
    int i = i0 + nl;
    float a[16] = {0,0,0,0,0,0,0,0,0,0,0,0,0,0,0,0};
    if (i < n) {
        int s = off[i], e2 = off[i + 1], j = s;
        for (; j + 1 < e2; j += 2) {
            size_t r0 = (size_t)csr[j] * 8, r1 = (size_t)csr[j + 1] * 8;
            u32x4 v0 = X4[r0 + c0], v1 = X4[r0 + c0 + 4];
            u32x4 w0 = X4[r1 + c0], w1 = X4[r1 + c0 + 4];
            acc8(a, v0); acc8(a + 8, v1); acc8(a, w0); acc8(a + 8, w1);
        }
        if (j < e2) {
            size_t r0 = (size_t)csr[j] * 8;
            acc8(a, X4[r0 + c0]); acc8(a + 8, X4[r0 + c0 + 4]);
        }
    }
    u32x4 o0, o1;
    o0.x = packb(a[0], a[1]);  o0.y = packb(a[2], a[3]);
    o0.z = packb(a[4], a[5]);  o0.w = packb(a[6], a[7]);
    o1.x = packb(a[8], a[9]);  o1.y = packb(a[10], a[11]);
    o1.z = packb(a[12], a[13]); o1.w = packb(a[14], a[15]);
    int sw = nl & 7;
    at4[nl * 8 + (c0 ^ sw)] = o0;
    at4[nl * 8 + ((c0 + 4) ^ sw)] = o1;
    int wave = t >> 6, lane = t & 63, quad = lane >> 4, nq = lane & 15;
    int arow = wave * 16 + nq;
    for (int e = 0; e < ENSN; e++) {
        __syncthreads();
        const u16* We = W0 + (size_t)e * DIM * FEAT;
        for (int ci = t; ci < 128 * 8; ci += 256) {
            int row = ci >> 3, c = ci & 7;
            wt4[row * 8 + (c ^ (row & 7))] = *(const u32x4*)(We + (size_t)row * FEAT + c * 8);
        }
        __syncthreads();
        floatx4 acc[8];
#pragma unroll
        for (int tt = 0; tt < 8; tt++) acc[tt] = (floatx4)(0.f);
#pragma unroll
        for (int kt = 0; kt < 2; kt++) {
            int ck = kt * 4 + quad;
            short8 af = *(const short8*)&at4[arow * 8 + (ck ^ (arow & 7))];
#pragma unroll
            for (int tt = 0; tt < 8; tt++) {
                int br = tt * 16 + nq;
                short8 bf = *(const short8*)&wt4[br * 8 + (ck ^ (br & 7))];
                acc[tt] = __builtin_amdgcn_mfma_f32_16x16x32_bf16(af, bf, acc[tt], 0, 0, 0);
            }
        }
        u16* Ye = Y + (size_t)e * (size_t)n * DIM;
#pragma unroll
        for (int tt = 0; tt < 8; tt++)
#pragma unroll
            for (int r = 0; r < 4; r++) {
                int row = i0 + wave * 16 + quad * 4 + r;
                if (row < n) Ye[(size_t)row * DIM + tt * 16 + nq] = f2b(fmaxf(acc[tt][r], 0.f));
            }
    }
}

// ---------------- layer-2 aggregation F=128, per-ens + COL-SPLIT (y = ENSN*2) ----------------
// SEPARATE from the GEMM on purpose: the gather needs high occupancy (72%) which the
// 64KB-LDS GEMM kernel cannot provide (R11: fused version fell to 20% occ, 2.0 TB/s).

__global__ __launch_bounds__(256) void aggb128cs_k(
        const u16* __restrict__ Hc, const int* __restrict__ offc, const int* __restrict__ csrc,
        u16* __restrict__ Yc, int nc,
        const u16* __restrict__ Hs, const int* __restrict__ offs, const int* __restrict__ csrs,
        u16* __restrict__ Ys, int ns) {
    int z = blockIdx.z;
    int n = z ? ns : nc;
    const int* off = z ? offs : offc;
    const int* csr = z ? csrs : csrc;
    int e = blockIdx.y >> 1, ch = blockIdx.y & 1;
    const u32x4* He = (const u32x4*)((z ? Hs : Hc) + (size_t)e * n * DIM);   // 16 chunks/row
    u32x4* Ye = (u32x4*)((z ? Ys : Yc) + (size_t)e * n * DIM);
    int i = blockIdx.x * 32 + (threadIdx.x >> 3);
    if (i >= n) return;
    int l8 = (threadIdx.x & 7) + ch * 8;
    int s = off[i], e2 = off[i + 1];
    float a[8] = {0.f, 0.f, 0.f, 0.f, 0.f, 0.f, 0.f, 0.f};
    int j = s;
    for (; j + 3 < e2; j += 4) {
        u32x4 v0 = He[(size_t)csr[j] * 16 + l8];
        u32x4 v1 = He[(size_t)csr[j + 1] * 16 + l8];
        u32x4 v2 = He[(size_t)csr[j + 2] * 16 + l8];
        u32x4 v3 = He[(size_t)csr[j + 3] * 16 + l8];
        acc8(a, v0); acc8(a, v1); acc8(a, v2); acc8(a, v3);
    }
    for (; j < e2; j++) acc8(a, He[(size_t)csr[j] * 16 + l8]);
    u32x4 o;
    o.x = packb(a[0], a[1]); o.y = packb(a[2], a[3]);
    o.z = packb(a[4], a[5]); o.w = packb(a[6], a[7]);
    Ye[(size_t)i * 16 + l8] = o;
}

// ---------------- fused GEMM2+GEMM3: p3 = (relu(A@W1)) @ W2 ----------------

__global__ __launch_bounds__(256) void gemm23_k(
        const u16* __restrict__ Xc, const u16* __restrict__ W1c, const u16* __restrict__ W2c,
        u16* __restrict__ Yc, int nc,
        const u16* __restrict__ Xs, const u16* __restrict__ W1s, const u16* __restrict__ W2s,
        u16* __restrict__ Ys, int ns) {
    __shared__ u16 wlds[DIM * DIM];
    __shared__ u16 hlds[4 * 32 * DIM];
    const int z = blockIdx.z, e = blockIdx.y;
    const int n = z ? ns : nc;
    const u16* Xe = (z ? Xs : Xc) + (size_t)e * (size_t)n * DIM;
    const u16* W1 = (z ? W1s : W1c) + (size_t)e * DIM * DIM;
    const u16* W2 = (z ? W2s : W2c) + (size_t)e * HALF * DIM;
    u16* Ye = (z ? Ys : Yc) + (size_t)e * (size_t)n * HALF;
    for (int c = threadIdx.x; c < DIM * (DIM / 8); c += 256) {
        int row = c >> 4, seg = c & 15;
        *(short8*)(wlds + row * DIM + ((seg ^ (row & 15)) << 3)) =
            *(const short8*)(W1 + (size_t)row * DIM + (seg << 3));
    }
    __syncthreads();
    int wave = threadIdx.x >> 6, lane = threadIdx.x & 63;
    int quad = lane >> 4, nq = lane & 15;
    int m0 = blockIdx.x * 128 + wave * 32;
    floatx4 acc[2][8];
#pragma unroll
    for (int rg = 0; rg < 2; rg++)
#pragma unroll
        for (int t = 0; t < 8; t++) acc[rg][t] = (floatx4)(0.f);
#pragma unroll
    for (int kt = 0; kt < 4; kt++) {
        int k0 = kt * 32 + quad * 8;
        short8 a[2];
#pragma unroll
        for (int rg = 0; rg < 2; rg++) {
            int row = m0 + rg * 16 + nq;
            int rc = row < n ? row : (n - 1);
            a[rg] = *(const short8*)(Xe + (size_t)rc * DIM + k0);
        }
#pragma unroll
        for (int t = 0; t < 8; t++) {
            int rb = t * 16 + nq;
            short8 b = *(const short8*)(wlds + rb * DIM + ((((kt << 2) + quad) ^ nq) << 3));
#pragma unroll
            for (int rg = 0; rg < 2; rg++)
                acc[rg][t] = __builtin_amdgcn_mfma_f32_16x16x32_bf16(a[rg], b, acc[rg][t], 0, 0, 0);
        }
    }
    u16* hw = hlds + wave * 32 * DIM;
#pragma unroll
    for (int rg = 0; rg < 2; rg++)
#pragma unroll
        for (int t = 0; t < 8; t++)
#pragma unroll
            for (int r = 0; r < 4; r++) {
                int rl = rg * 16 + quad * 4 + r;
                int col = t * 16 + nq;
                hw[rl * DIM + (((col >> 3) ^ (rl & 15)) << 3) + (col & 7)] =
                    f2b(fmaxf(acc[rg][t][r], 0.f));
            }
    __syncthreads();
    for (int c = threadIdx.x; c < HALF * (DIM / 8); c += 256) {
        int row = c >> 4, seg = c & 15;
        *(short8*)(wlds + row * DIM + ((seg ^ (row & 15)) << 3)) =
            *(const short8*)(W2 + (size_t)row * DIM + (seg << 3));
    }
    __syncthreads();
    floatx4 acc2[2][4];
#pragma unroll
    for (int rg = 0; rg < 2; rg++)
#pragma unroll
        for (int t = 0; t < 4; t++) acc2[rg][t] = (floatx4)(0.f);
#pragma unroll
    for (int kt = 0; kt < 4; kt++) {
        int k0q = (kt << 2) + quad;
        short8 a[2];
#pragma unroll
        for (int rg = 0; rg < 2; rg++) {
            int rl = rg * 16 + nq;
            a[rg] = *(const short8*)(hw + rl * DIM + ((k0q ^ (rl & 15)) << 3));
        }
#pragma unroll
        for (int t = 0; t < 4; t++) {
            int rb = t * 16 + nq;
            short8 b = *(const short8*)(wlds + rb * DIM + ((k0q ^ nq) << 3));
#pragma unroll
            for (int rg = 0; rg < 2; rg++)
                acc2[rg][t] = __builtin_amdgcn_mfma_f32_16x16x32_bf16(a[rg], b, acc2[rg][t], 0, 0, 0);
        }
    }
#pragma unroll
    for (int rg = 0; rg < 2; rg++)
#pragma unroll
        for (int t = 0; t < 4; t++)
#pragma unroll
            for (int r = 0; r < 4; r++) {
                int row = m0 + rg * 16 + quad * 4 + r;
                if (row < n) Ye[(size_t)row * HALF + t * 16 + nq] = f2b(acc2[rg][t][r]);
            }
}

// ---------------- layer-3 agg + relu + pool, PER-ENS ----------------

__global__ __launch_bounds__(256) void agg3pool_k(
        const u16* __restrict__ Pc, const int* __restrict__ offc, const int* __restrict__ csrc,
        const int* __restrict__ batc, int nc,
        const u16* __restrict__ Ps, const int* __restrict__ offs, const int* __restrict__ csrs,
        const int* __restrict__ bats, int ns,
        float* __restrict__ rep) {
    int z = blockIdx.z, e = blockIdx.y;
    int n = z ? ns : nc;
    const int* off = z ? offs : offc;
    const int* csr = z ? csrs : csrc;
    const int* batch = z ? bats : batc;
    const u32x4* Pe = (const u32x4*)((z ? Ps : Pc) + (size_t)e * (size_t)n * HALF);  // 8 chunks/row
    int i0 = blockIdx.x * 32;
    int nl = threadIdx.x >> 3, l8 = threadIdx.x & 7;
    int i = i0 + nl;
    float a[8] = {0,0,0,0,0,0,0,0};
    if (i < n) {
        int s = off[i], e2 = off[i + 1], j = s;
        for (; j + 3 < e2; j += 4) {
            u32x4 v0 = Pe[(size_t)csr[j] * 8 + l8];
            u32x4 v1 = Pe[(size_t)csr[j + 1] * 8 + l8];
            u32x4 v2 = Pe[(size_t)csr[j + 2] * 8 + l8];
            u32x4 v3 = Pe[(size_t)csr[j + 3] * 8 + l8];
            acc8(a, v0); acc8(a, v1); acc8(a, v2); acc8(a, v3);
        }
        for (; j < e2; j++) acc8(a, Pe[(size_t)csr[j] * 8 + l8]);
    }
    __shared__ float sm[32][64];
    __shared__ int gb[32];
#pragma unroll
    for (int k = 0; k < 8; k++) sm[nl][l8 * 8 + k] = fmaxf(a[k], 0.f);
    if (threadIdx.x < 32) gb[threadIdx.x] = (i0 + (int)threadIdx.x < n) ? batch[i0 + threadIdx.x] : -1;
    __syncthreads();
    if (threadIdx.x < 64) {
        int f = threadIdx.x;
        int colbase = z * (ENSN * HALF) + e * HALF + f;
        float acc = 0.f;
        int g = -2;
        for (int k = 0; k < 32; k++) {
            int gg = gb[k];
            if (gg != g) {
                if (g >= 0) atomicAdd(&rep[g * (2 * ENSN * HALF) + colbase], acc);
                acc = 0.f;
                g = gg;
            }
            if (gg >= 0) acc += sm[k][f];
        }
        if (g >= 0) atomicAdd(&rep[g * (2 * ENSN * HALF) + colbase], acc);
    }
}

// ---------------- fused heads + final MLP: one block per graph ----------------

__global__ __launch_bounds__(256) void headfinal_k(
        const float* __restrict__ rep,
        const float* __restrict__ cW, const float* __restrict__ cB,
        const float* __restrict__ sW, const float* __restrict__ sB,
        const float* __restrict__ W1, const float* __restrict__ b1,
        const float* __restrict__ W2, const float* __restrict__ b2,
        float* __restrict__ out) {
    int b = blockIdx.x, t = threadIdx.x;
    __shared__ float r[2 * ENSN * HALF];
    __shared__ float hg[2 * ENSN * DIM];
    __shared__ float red[DIM];
    for (int i = t; i < 2 * ENSN * HALF; i += 256) r[i] = rep[b * (2 * ENSN * HALF) + i];
    __syncthreads();
    for (int o = t; o < 2 * ENSN * DIM; o += 256) {
        int head = o >> 7, c = o & 127;
        int branch = head / ENSN, e = head - branch * ENSN;
        const float* W = (branch ? sW : cW) + (size_t)e * HALF * DIM;
        const float* rr = r + branch * (ENSN * HALF) + e * HALF;
        float acc = (branch ? sB : cB)[e * DIM + c];
#pragma unroll
        for (int k = 0; k < HALF; k++) acc = fmaf(rr[k], W[k * DIM + c], acc);
        hg[o] = fmaxf(acc, 0.f);
    }
    __syncthreads();
    if (t < DIM) {
        float acc = b1[t];
        for (int k = 0; k < 2 * ENSN * DIM; k++) acc = fmaf(hg[k], W1[k * DIM + t], acc);
        red[t] = fmaxf(acc, 0.f) * W2[t];
    }
    __syncthreads();
    if (t < 64) {
        float v = red[t] + red[t + 64];
#pragma unroll
        for (int o = 32; o > 0; o >>= 1) v += __shfl_down(v, o, 64);
        if (t == 0) out[b] = v + b2[0];
    }
}

// ---------------- host ----------------

extern "C" void kernel_launch(void* const* d_in, const int* in_sizes, int n_in,
                              void* d_out, int out_size, void* d_ws, size_t ws_size,
                              hipStream_t stream) {
    const float* chr_x = (const float*)d_in[0];
    const float* slv_x = (const float*)d_in[1];
    const int* chr_ei = (const int*)d_in[2];
    const int* slv_ei = (const int*)d_in[3];
    const int* chr_batch = (const int*)d_in[4];
    const int* slv_batch = (const int*)d_in[5];
    const float* chr_W0 = (const float*)d_in[6];
    const float* chr_W1 = (const float*)d_in[7];
    const float* chr_W2 = (const float*)d_in[8];
    const float* slv_W0 = (const float*)d_in[9];
    const float* slv_W1 = (const float*)d_in[10];
    const float* slv_W2 = (const float*)d_in[11];
    const float* cfc_W = (const float*)d_in[12];
    const float* cfc_b = (const float*)d_in[13];
    const float* sfc_W = (const float*)d_in[14];
    const float* sfc_b = (const float*)d_in[15];
    const float* fc1_W = (const float*)d_in[16];
    const float* fc1_b = (const float*)d_in[17];
    const float* fc2_W = (const float*)d_in[18];
    const float* fc2_b = (const float*)d_in[19];
    float* out = (float*)d_out;

    char* w = (char*)d_ws;
    auto carve = [&](size_t bytes) {
        void* p = (void*)w;
        w += (bytes + 255) & ~(size_t)255;
        return p;
    };
    int* off_chr = (int*)carve((N_CHR + 1) * sizeof(int));
    int* csr_chr = (int*)carve((size_t)E_CHR * sizeof(int));
    int* off_slv = (int*)carve((N_SLV + 1) * sizeof(int));
    int* csr_slv = (int*)carve((size_t)E_SLV * sizeof(int));
    int* btot    = (int*)carve(CB_TOT * sizeof(int));
    int* coff    = (int*)carve((CB_TOT + 1) * sizeof(int));
    int* gh      = (int*)carve((size_t)CB_TOT * SLOTS * sizeof(int));
    u32* staging = (u32*)carve((size_t)E_TOT * sizeof(u32));
    u16* cW0t = (u16*)carve((size_t)ENSN * DIM * FEAT * sizeof(u16));
    u16* cW1t = (u16*)carve((size_t)ENSN * DIM * DIM * sizeof(u16));
    u16* cW2t = (u16*)carve((size_t)ENSN * HALF * DIM * sizeof(u16));
    u16* sW0t = (u16*)carve((size_t)ENSN * DIM * FEAT * sizeof(u16));
    u16* sW1t = (u16*)carve((size_t)ENSN * DIM * DIM * sizeof(u16));
    u16* sW2t = (u16*)carve((size_t)ENSN * HALF * DIM * sizeof(u16));
    u16* xb_chr = (u16*)carve((size_t)N_CHR * FEAT * sizeof(u16));
    u16* xb_slv = (u16*)carve((size_t)N_SLV * FEAT * sizeof(u16));
    float* rep = (float*)carve((size_t)REP_SZ * sizeof(float));
    u16* bufP_c = (u16*)carve((size_t)ENSN * N_CHR * DIM * sizeof(u16));   // h1, later p3
    u16* bufQ_c = (u16*)carve((size_t)ENSN * N_CHR * DIM * sizeof(u16));   // agg(h1)
    u16* bufP_s = (u16*)carve((size_t)ENSN * N_SLV * DIM * sizeof(u16));
    u16* bufQ_s = (u16*)carve((size_t)ENSN * N_SLV * DIM * sizeof(u16));

    // ---- converts (xconv also zeros btot) ----
    xconv_k<<<512, 256, 0, stream>>>(chr_x, slv_x, xb_chr, xb_slv, btot);
    wconv6_k<<<dim3(64, ENSN, 6), 256, 0, stream>>>(chr_W0, chr_W1, chr_W2,
                                                    slv_W0, slv_W1, slv_W2,
                                                    cW0t, cW1t, cW2t, sW0t, sW1t, sW2t);

    // ---- CSR build (hist also zeros rep) ----
    hist_blocks_k<<<NBLK, 256, 0, stream>>>(chr_ei + E_CHR, slv_ei + E_SLV, gh, btot, rep);
    coarse_scan_k<<<1, 64, 0, stream>>>(btot, coff);
    block_base_k<<<CB_TOT, 256, 0, stream>>>(gh, coff);
    scatter2_k<<<NBLK, 256, 0, stream>>>(chr_ei, slv_ei, gh, staging);
    bucket_sort_k<<<CB_TOT, 256, 0, stream>>>(staging, coff, off_chr, off_slv, csr_chr, csr_slv);

    // ---- branches (chr+slv via z; ens/col-split via y) ----
    agg1gemm_k<<<dim3((N_CHR + 63) / 64, 1, 2), 256, 0, stream>>>(
        xb_chr, off_chr, csr_chr, cW0t, bufP_c, N_CHR,
        xb_slv, off_slv, csr_slv, sW0t, bufP_s, N_SLV);
    aggb128cs_k<<<dim3((N_CHR + 31) / 32, ENSN * 2, 2), 256, 0, stream>>>(
        bufP_c, off_chr, csr_chr, bufQ_c, N_CHR,
        bufP_s, off_slv, csr_slv, bufQ_s, N_SLV);
    gemm23_k<<<dim3((N_CHR + 127) / 128, ENSN, 2), 256, 0, stream>>>(
        bufQ_c, cW1t, cW2t, bufP_c, N_CHR,
        bufQ_s, sW1t, sW2t, bufP_s, N_SLV);                  // p3 overwrites h1
    agg3pool_k<<<dim3((N_CHR + 31) / 32, ENSN, 2), 256, 0, stream>>>(
        bufP_c, off_chr, csr_chr, chr_batch, N_CHR,
        bufP_s, off_slv, csr_slv, slv_batch, N_SLV, rep);

    // ---- heads + final MLP ----
    headfinal_k<<<BATCH_B, 256, 0, stream>>>(rep, cfc_W, cfc_b, sfc_W, sfc_b,
                                             fc1_W, fc1_b, fc2_W, fc2_b, out);
}